// Round 9
// baseline (8873.727 us; speedup 1.0000x reference)
//
#include <hip/hip_runtime.h>
#include <stdint.h>

#define TSTEPS 512
#define BATCH  32
#define HID    512
#define G4     2048
#define OUTW   1024
#define MTOT   (TSTEPS * BATCH)   // 16384, m = t*32 + b

#define HROW   1040               // padded LDS row stride (bytes)
#define HPLANE (32 * HROW)        // 33280 B ; planes: d0hi d0lo d1hi d1lo
#define ZW     36                 // ZL row stride (floats), rows = zc, cols = batch

typedef __attribute__((ext_vector_type(8))) short bf16x8;
typedef __attribute__((ext_vector_type(4))) float f32x4;

__device__ __forceinline__ float sigf(float x) { return 1.0f / (1.0f + __expf(-x)); }
__device__ __forceinline__ float tanhf_fast(float x) { return 2.0f / (1.0f + __expf(-2.0f * x)) - 1.0f; }

__device__ __forceinline__ unsigned short f2bf(float f) {
    unsigned int u = __float_as_uint(f);
    u += 0x7fffu + ((u >> 16) & 1u);
    return (unsigned short)(u >> 16);
}
__device__ __forceinline__ float bf2f(unsigned short u) {
    return __uint_as_float((unsigned int)u << 16);
}
__device__ __forceinline__ void addxw(f32x4& a, uint2 u) {
    a.x += bf2f((unsigned short)(u.x & 0xffff));
    a.y += bf2f((unsigned short)(u.x >> 16));
    a.z += bf2f((unsigned short)(u.y & 0xffff));
    a.w += bf2f((unsigned short)(u.y >> 16));
}

// ---------------------------------------------------------------------------
// MFMA input-projection GEMM (proven R7), transposed bf16 XWt[n][m].
// ---------------------------------------------------------------------------
__global__ __launch_bounds__(256) void gemm_xw_mfma(
    const float* __restrict__ X, int K,
    const float* __restrict__ W,
    const float* __restrict__ bias,
    unsigned short* __restrict__ XWt)
{
    extern __shared__ char gsm[];
    char* Abuf = gsm;
    char* Bbuf = gsm + 18432;

    const int tid = threadIdx.x;
    const int n0 = blockIdx.x * 128;
    const int m0 = blockIdx.y * 128;
    const int w  = tid >> 6;
    const int l  = tid & 63;
    const int lc16 = l & 15;
    const int lq4  = l >> 4;
    const int wr = w >> 1, wc = w & 1;

    const int ar  = tid >> 1;
    const int akh = tid & 1;
    const int mg  = m0 + ar;
    const float* aptr = X + (size_t)(mg & 31) * ((size_t)TSTEPS * K)
                          + (size_t)(mg >> 5) * K + akh * 16;
    const int bnp = tid & 63;
    const int bkg = tid >> 6;
    const float* bptr = W + n0 + bnp * 2;

    f32x4 acc[4][4];
    #pragma unroll
    for (int i = 0; i < 4; ++i)
        #pragma unroll
        for (int j = 0; j < 4; ++j) acc[i][j] = (f32x4){0.f, 0.f, 0.f, 0.f};

    const int KT = K >> 5;
    float4 a0, a1, a2, a3;
    float2 bw[8];

#define GLOADS(KT0) do { \
    const float* ap = aptr + (KT0) * 32; \
    a0 = *(const float4*)(ap);      a1 = *(const float4*)(ap + 4); \
    a2 = *(const float4*)(ap + 8);  a3 = *(const float4*)(ap + 12); \
    _Pragma("unroll") \
    for (int i = 0; i < 8; ++i) \
        bw[i] = *(const float2*)(bptr + (size_t)((KT0) * 32 + bkg * 8 + i) * G4); \
} while (0)

    GLOADS(0);

    for (int kt = 0; kt < KT; ++kt) {
        __syncthreads();
        {
            float av[16] = {a0.x,a0.y,a0.z,a0.w, a1.x,a1.y,a1.z,a1.w,
                            a2.x,a2.y,a2.z,a2.w, a3.x,a3.y,a3.z,a3.w};
            bf16x8 h0, h1, l0, l1;
            #pragma unroll
            for (int i = 0; i < 8; ++i) {
                unsigned short hh = f2bf(av[i]);
                h0[i] = (short)hh; l0[i] = (short)f2bf(av[i] - bf2f(hh));
                unsigned short hh2 = f2bf(av[i + 8]);
                h1[i] = (short)hh2; l1[i] = (short)f2bf(av[i + 8] - bf2f(hh2));
            }
            char* ab = Abuf + ar * 144 + akh * 32;
            *(bf16x8*)(ab)      = h0;
            *(bf16x8*)(ab + 16) = h1;
            *(bf16x8*)(ab + 64) = l0;
            *(bf16x8*)(ab + 80) = l1;
        }
        {
            bf16x8 bh[2], bl[2];
            #pragma unroll
            for (int c = 0; c < 2; ++c) {
                #pragma unroll
                for (int i = 0; i < 8; ++i) {
                    float v = c ? bw[i].y : bw[i].x;
                    unsigned short hh = f2bf(v);
                    bh[c][i] = (short)hh;
                    bl[c][i] = (short)f2bf(v - bf2f(hh));
                }
                char* bb = Bbuf + (bnp * 2 + c) * 144 + bkg * 16;
                *(bf16x8*)(bb)      = bh[c];
                *(bf16x8*)(bb + 64) = bl[c];
            }
        }
        __syncthreads();
        if (kt + 1 < KT) GLOADS(kt + 1);

        bf16x8 ah[4], al[4], bh[4], bl[4];
        #pragma unroll
        for (int rt = 0; rt < 4; ++rt) {
            const char* ab = Abuf + (wr * 64 + rt * 16 + lc16) * 144 + lq4 * 16;
            ah[rt] = *(const bf16x8*)(ab);
            al[rt] = *(const bf16x8*)(ab + 64);
        }
        #pragma unroll
        for (int ct = 0; ct < 4; ++ct) {
            const char* bb = Bbuf + (wc * 64 + ct * 16 + lc16) * 144 + lq4 * 16;
            bh[ct] = *(const bf16x8*)(bb);
            bl[ct] = *(const bf16x8*)(bb + 64);
        }
        #pragma unroll
        for (int rt = 0; rt < 4; ++rt)
            #pragma unroll
            for (int ct = 0; ct < 4; ++ct) {
                acc[rt][ct] = __builtin_amdgcn_mfma_f32_16x16x32_bf16(ah[rt], bh[ct], acc[rt][ct], 0, 0, 0);
                acc[rt][ct] = __builtin_amdgcn_mfma_f32_16x16x32_bf16(al[rt], bh[ct], acc[rt][ct], 0, 0, 0);
                acc[rt][ct] = __builtin_amdgcn_mfma_f32_16x16x32_bf16(ah[rt], bl[ct], acc[rt][ct], 0, 0, 0);
            }
    }
#undef GLOADS

    #pragma unroll
    for (int ct = 0; ct < 4; ++ct) {
        const int n = n0 + wc * 64 + ct * 16 + lc16;
        const float bn = bias[n];
        #pragma unroll
        for (int rt = 0; rt < 4; ++rt) {
            const int m = m0 + wr * 64 + rt * 16 + lq4 * 4;
            f32x4 v = acc[rt][ct];
            uint2 pk;
            pk.x = (unsigned)f2bf(v.x + bn) | ((unsigned)f2bf(v.y + bn) << 16);
            pk.y = (unsigned)f2bf(v.z + bn) | ((unsigned)f2bf(v.w + bn) << 16);
            *(uint2*)(XWt + (size_t)n * MTOT + m) = pk;
        }
    }
}

// ---------------------------------------------------------------------------
// Dual-direction MFMA scan, single-flag protocol. 32 blocks x 256 thr, 1/CU.
// Block B owns h-cols [B*16, B*16+16) of BOTH dirs. Wave w = gate w.
// Per iter: poll(s-1) -> 32 MALL loads -> stage both dirs -> bar ->
//           MFMA d0+d1 -> ZL0/ZL1 -> bar -> fused gates -> publish both ->
//           vmcnt(0) -> bar -> one flag store.  (3 barriers, 1 poll, 1 drain)
// LDS: 4 h-planes 133120 B + ZL0/ZL1 18432 B = 151552 B.
// ---------------------------------------------------------------------------
__global__ __launch_bounds__(256, 1) void lstm_scan8(
    const unsigned short* __restrict__ xw_f,   // [G4][MTOT] bf16
    const unsigned short* __restrict__ xw_b,
    const float* __restrict__ Wh_f,            // [512][2048] f32
    const float* __restrict__ Wh_b,
    float* __restrict__ out,                   // [B][T][1024] f32
    unsigned short* __restrict__ hbuf,         // [dir][par][plane][P][b][16c] bf16
    int* __restrict__ flags,                   // [TSTEPS][32] int
    int lval)
{
    extern __shared__ char smem[];
    float* ZL0 = (float*)(smem + 4 * HPLANE);  // [64 zc][36]
    float* ZL1 = ZL0 + 64 * ZW;

    const int tid  = threadIdx.x;
    const int l    = tid & 63;
    const int w    = tid >> 6;                 // gate 0..3
    const int B    = blockIdx.x;               // h-col slice 0..31
    const int lc16 = l & 15;
    const int lq4  = l >> 4;
    const int col  = w * 512 + B * 16 + lc16;  // global z-col

    // ---- one-time: Wh fragments (both dirs) -> registers, hi/lo bf16 ----
    bf16x8 w0h[16], w0l[16], w1h[16], w1l[16];
    #pragma unroll
    for (int ki = 0; ki < 16; ++ki) {
        const float* s0 = Wh_f + (size_t)(ki * 32 + lq4 * 8) * G4 + col;
        const float* s1 = Wh_b + (size_t)(ki * 32 + lq4 * 8) * G4 + col;
        bf16x8 vh0, vl0, vh1, vl1;
        #pragma unroll
        for (int r = 0; r < 8; ++r) {
            float v = s0[(size_t)r * G4];
            unsigned short h16 = f2bf(v);
            vh0[r] = (short)h16; vl0[r] = (short)f2bf(v - bf2f(h16));
            float u = s1[(size_t)r * G4];
            unsigned short h17 = f2bf(u);
            vh1[r] = (short)h17; vl1[r] = (short)f2bf(u - bf2f(h17));
        }
        w0h[ki] = vh0; w0l[ki] = vl0; w1h[ki] = vh1; w1l[ki] = vl1;
    }

    const unsigned short* xc0 = xw_f + (size_t)col * MTOT;
    const unsigned short* xc1 = xw_b + (size_t)col * MTOT;
    char* hb0 = (char*)hbuf;                   // 131072 B per dir
    char* hb1 = (char*)hbuf + 131072;

    const int gb = tid & 31;                   // gate-thread batch
    const int jp = tid >> 5;                   // col-pair 0..7 (local cols jp*2, jp*2+1)
    float cq00 = 0.f, cq01 = 0.f, cq10 = 0.f, cq11 = 0.f;
    float* outb = out + (size_t)gb * TSTEPS * OUTW + B * 16 + jp * 2;

    for (int s = 0; s < TSTEPS; ++s) {
        const int t0 = s, t1 = TSTEPS - 1 - s;

        uint2 x00 = *(const uint2*)(xc0 + t0 * 32 + lq4 * 4);
        uint2 x01 = *(const uint2*)(xc0 + t0 * 32 + lq4 * 4 + 16);
        uint2 x10 = *(const uint2*)(xc1 + t1 * 32 + lq4 * 4);
        uint2 x11 = *(const uint2*)(xc1 + t1 * 32 + lq4 * 4 + 16);

        f32x4 a00 = {0,0,0,0}, a01 = {0,0,0,0}, a10 = {0,0,0,0}, a11 = {0,0,0,0};

        if (s > 0) {
            // ---- single poll: step s-1 complete (both dirs) ----
            {
                const int* fp = flags + (s - 1) * 32 + (l & 31);
                int fv;
                do {
                    asm volatile("global_load_dword %0, %1, off sc0 sc1\n\t"
                                 "s_waitcnt vmcnt(0)"
                                 : "=v"(fv) : "v"(fp) : "memory");
                } while (__any(fv != lval));
            }
            // ---- one burst: 32 MALL loads (16 per dir) ----
            const char* h0src = hb0 + ((s - 1) & 1) * 65536;
            const char* h1src = hb1 + ((s - 1) & 1) * 65536;
            float4 rg[16], rh[16];
            #pragma unroll
            for (int c = 0; c < 16; ++c)
                asm volatile("global_load_dwordx4 %0, %1, off sc0 sc1"
                             : "=v"(rg[c]) : "v"(h0src + c * 4096 + tid * 16) : "memory");
            #pragma unroll
            for (int c = 0; c < 16; ++c)
                asm volatile("global_load_dwordx4 %0, %1, off sc0 sc1"
                             : "=v"(rh[c]) : "v"(h1src + c * 4096 + tid * 16) : "memory");
            asm volatile("s_waitcnt vmcnt(16)" ::: "memory");
            __builtin_amdgcn_sched_barrier(0);
            #pragma unroll
            for (int c = 0; c < 16; ++c) {
                const int ip = (c & 7) * 4096 + tid * 16;
                const int P = ip >> 10, b = (ip >> 5) & 31, cb = ip & 31;
                *(float4*)(smem + (c >> 3) * HPLANE + b * HROW + P * 32 + cb) = rg[c];
            }
            asm volatile("s_waitcnt vmcnt(0)" ::: "memory");
            __builtin_amdgcn_sched_barrier(0);
            #pragma unroll
            for (int c = 0; c < 16; ++c) {
                const int ip = (c & 7) * 4096 + tid * 16;
                const int P = ip >> 10, b = (ip >> 5) & 31, cb = ip & 31;
                *(float4*)(smem + 2 * HPLANE + (c >> 3) * HPLANE + b * HROW + P * 32 + cb) = rh[c];
            }
        }
        __syncthreads();                               // [bar 1] stage visible

        if (s > 0) {
            #pragma unroll
            for (int ki = 0; ki < 16; ++ki) {
                const int ko = ki * 64 + lq4 * 16;
                const char* r0 = smem + (size_t)lc16 * HROW + ko;
                const char* r1 = smem + (size_t)(lc16 + 16) * HROW + ko;
                bf16x8 ah0 = *(const bf16x8*)r0;
                bf16x8 ah1 = *(const bf16x8*)r1;
                bf16x8 al0 = *(const bf16x8*)(r0 + HPLANE);
                bf16x8 al1 = *(const bf16x8*)(r1 + HPLANE);
                a00 = __builtin_amdgcn_mfma_f32_16x16x32_bf16(ah0, w0h[ki], a00, 0, 0, 0);
                a01 = __builtin_amdgcn_mfma_f32_16x16x32_bf16(ah1, w0h[ki], a01, 0, 0, 0);
                a00 = __builtin_amdgcn_mfma_f32_16x16x32_bf16(al0, w0h[ki], a00, 0, 0, 0);
                a01 = __builtin_amdgcn_mfma_f32_16x16x32_bf16(al1, w0h[ki], a01, 0, 0, 0);
                a00 = __builtin_amdgcn_mfma_f32_16x16x32_bf16(ah0, w0l[ki], a00, 0, 0, 0);
                a01 = __builtin_amdgcn_mfma_f32_16x16x32_bf16(ah1, w0l[ki], a01, 0, 0, 0);
                const char* q0 = r0 + 2 * HPLANE;
                const char* q1 = r1 + 2 * HPLANE;
                bf16x8 bh0 = *(const bf16x8*)q0;
                bf16x8 bh1 = *(const bf16x8*)q1;
                bf16x8 bl0 = *(const bf16x8*)(q0 + HPLANE);
                bf16x8 bl1 = *(const bf16x8*)(q1 + HPLANE);
                a10 = __builtin_amdgcn_mfma_f32_16x16x32_bf16(bh0, w1h[ki], a10, 0, 0, 0);
                a11 = __builtin_amdgcn_mfma_f32_16x16x32_bf16(bh1, w1h[ki], a11, 0, 0, 0);
                a10 = __builtin_amdgcn_mfma_f32_16x16x32_bf16(bl0, w1h[ki], a10, 0, 0, 0);
                a11 = __builtin_amdgcn_mfma_f32_16x16x32_bf16(bl1, w1h[ki], a11, 0, 0, 0);
                a10 = __builtin_amdgcn_mfma_f32_16x16x32_bf16(bh0, w1l[ki], a10, 0, 0, 0);
                a11 = __builtin_amdgcn_mfma_f32_16x16x32_bf16(bh1, w1l[ki], a11, 0, 0, 0);
            }
        }

        addxw(a00, x00); addxw(a01, x01);
        addxw(a10, x10); addxw(a11, x11);
        {
            const int zc = w * 16 + lc16;
            *(f32x4*)&ZL0[zc * ZW + lq4 * 4]      = a00;
            *(f32x4*)&ZL0[zc * ZW + 16 + lq4 * 4] = a01;
            *(f32x4*)&ZL1[zc * ZW + lq4 * 4]      = a10;
            *(f32x4*)&ZL1[zc * ZW + 16 + lq4 * 4] = a11;
        }
        __syncthreads();                               // [bar 2] z visible

        // ---- fused gates, both dirs; publish h ----
        float h00, h01, h10, h11;
        {
            const int j0 = jp * 2, j1 = jp * 2 + 1;
            float zi0 = ZL0[j0 * ZW + gb],        zi1 = ZL0[j1 * ZW + gb];
            float zf0 = ZL0[(16 + j0) * ZW + gb], zf1 = ZL0[(16 + j1) * ZW + gb];
            float zg0 = ZL0[(32 + j0) * ZW + gb], zg1 = ZL0[(32 + j1) * ZW + gb];
            float zo0 = ZL0[(48 + j0) * ZW + gb], zo1 = ZL0[(48 + j1) * ZW + gb];
            cq00 = fmaf(sigf(zf0), cq00, sigf(zi0) * tanhf_fast(zg0));
            cq01 = fmaf(sigf(zf1), cq01, sigf(zi1) * tanhf_fast(zg1));
            h00 = sigf(zo0) * tanhf_fast(cq00);
            h01 = sigf(zo1) * tanhf_fast(cq01);
            float yi0 = ZL1[j0 * ZW + gb],        yi1 = ZL1[j1 * ZW + gb];
            float yf0 = ZL1[(16 + j0) * ZW + gb], yf1 = ZL1[(16 + j1) * ZW + gb];
            float yg0 = ZL1[(32 + j0) * ZW + gb], yg1 = ZL1[(32 + j1) * ZW + gb];
            float yo0 = ZL1[(48 + j0) * ZW + gb], yo1 = ZL1[(48 + j1) * ZW + gb];
            cq10 = fmaf(sigf(yf0), cq10, sigf(yi0) * tanhf_fast(yg0));
            cq11 = fmaf(sigf(yf1), cq11, sigf(yi1) * tanhf_fast(yg1));
            h10 = sigf(yo0) * tanhf_fast(cq10);
            h11 = sigf(yo1) * tanhf_fast(cq11);

            unsigned short b00 = f2bf(h00), b01 = f2bf(h01);
            unsigned short b10 = f2bf(h10), b11 = f2bf(h11);
            unsigned int hi0 = (unsigned)b00 | ((unsigned)b01 << 16);
            unsigned int lo0 = (unsigned)f2bf(h00 - bf2f(b00)) |
                               ((unsigned)f2bf(h01 - bf2f(b01)) << 16);
            unsigned int hi1 = (unsigned)b10 | ((unsigned)b11 << 16);
            unsigned int lo1 = (unsigned)f2bf(h10 - bf2f(b10)) |
                               ((unsigned)f2bf(h11 - bf2f(b11)) << 16);
            const int boff = (s & 1) * 65536 + B * 1024 + gb * 32 + jp * 4;
            char* wp0 = hb0 + boff;
            char* wp1 = hb1 + boff;
            asm volatile("global_store_dword %0, %1, off sc0 sc1" :: "v"(wp0), "v"(hi0) : "memory");
            asm volatile("global_store_dword %0, %1, off sc0 sc1" :: "v"(wp0 + 32768), "v"(lo0) : "memory");
            asm volatile("global_store_dword %0, %1, off sc0 sc1" :: "v"(wp1), "v"(hi1) : "memory");
            asm volatile("global_store_dword %0, %1, off sc0 sc1" :: "v"(wp1 + 32768), "v"(lo1) : "memory");
        }
        asm volatile("s_waitcnt vmcnt(0)" ::: "memory");
        __syncthreads();                               // [bar 3] all publishes drained
        if (tid == 0) {
            const int* fp = flags + s * 32 + B;
            asm volatile("global_store_dword %0, %1, off sc0 sc1"
                         :: "v"(fp), "v"(lval) : "memory");
        }

        // ---- output stores (cached, off the critical path) ----
        {
            float2 o0; o0.x = h00; o0.y = h01;
            float2 o1; o1.x = h10; o1.y = h11;
            *(float2*)(outb + (size_t)t0 * OUTW)       = o0;
            *(float2*)(outb + (size_t)t1 * OUTW + HID) = o1;
        }
    }
}

extern "C" void kernel_launch(void* const* d_in, const int* in_sizes, int n_in,
                              void* d_out, int out_size, void* d_ws, size_t ws_size,
                              hipStream_t stream)
{
    const float* x     = (const float*)d_in[0];
    const float* Wi_f0 = (const float*)d_in[1];
    const float* Wh_f0 = (const float*)d_in[2];
    const float* b_f0  = (const float*)d_in[3];
    const float* Wi_b0 = (const float*)d_in[4];
    const float* Wh_b0 = (const float*)d_in[5];
    const float* b_b0  = (const float*)d_in[6];
    const float* Wi_f1 = (const float*)d_in[7];
    const float* Wh_f1 = (const float*)d_in[8];
    const float* b_f1  = (const float*)d_in[9];
    const float* Wi_b1 = (const float*)d_in[10];
    const float* Wh_b1 = (const float*)d_in[11];
    const float* b_b1  = (const float*)d_in[12];
    float* out = (float*)d_out;

    const size_t xw_elems = (size_t)MTOT * G4;                 // 33,554,432
    unsigned short* xwf = (unsigned short*)d_ws;
    unsigned short* xwb = xwf + xw_elems;
    char* tail = (char*)d_ws + 2 * xw_elems * sizeof(unsigned short);  // 128 MiB
    unsigned short* hbuf = (unsigned short*)tail;              // 256 KiB
    int* flags = (int*)(tail + 262144);                        // [512][32] int = 64 KiB

    (void)hipMemsetAsync(flags, 0, TSTEPS * 32 * sizeof(int), stream);

    dim3 ggrid(G4 / 128, MTOT / 128);                          // (16, 128)
    dim3 gblock(256);
    const size_t gsmem = 36864;
    dim3 sgrid(32);                                            // both dirs per block
    dim3 sblock(256);
    const size_t ssmem = 4 * HPLANE + 2 * 64 * ZW * 4;         // 151,552 B

    gemm_xw_mfma<<<ggrid, gblock, gsmem, stream>>>(x, 256, Wi_f0, b_f0, xwf);
    gemm_xw_mfma<<<ggrid, gblock, gsmem, stream>>>(x, 256, Wi_b0, b_b0, xwb);
    lstm_scan8<<<sgrid, sblock, ssmem, stream>>>(xwf, xwb, Wh_f0, Wh_b0, out,
                                                 hbuf, flags, 1);
    gemm_xw_mfma<<<ggrid, gblock, gsmem, stream>>>(out, 1024, Wi_f1, b_f1, xwf);
    gemm_xw_mfma<<<ggrid, gblock, gsmem, stream>>>(out, 1024, Wi_b1, b_b1, xwb);
    lstm_scan8<<<sgrid, sblock, ssmem, stream>>>(xwf, xwb, Wh_f1, Wh_b1, out,
                                                 hbuf, flags, 2);
}

// Round 10
// 5289.703 us; speedup vs baseline: 1.6775x; 1.6775x over previous
//
#include <hip/hip_runtime.h>
#include <stdint.h>

#define TSTEPS 512
#define BATCH  32
#define HID    512
#define G4     2048
#define OUTW   1024
#define MTOT   (TSTEPS * BATCH)   // 16384, m = t*32 + b

#define NBLK   16                 // scan blocks per direction
#define KROW   528                // HST row stride (bytes): 64 k16-rows x [32 b x 16B]
#define HSZ    (64 * KROW)        // 33792 B (single hi plane)

typedef __attribute__((ext_vector_type(8))) short bf16x8;
typedef __attribute__((ext_vector_type(4))) float f32x4;

__device__ __forceinline__ float sigf(float x) { return 1.0f / (1.0f + __expf(-x)); }
__device__ __forceinline__ float tanhf_fast(float x) { return 2.0f / (1.0f + __expf(-2.0f * x)) - 1.0f; }

__device__ __forceinline__ unsigned short f2bf(float f) {
    unsigned int u = __float_as_uint(f);
    u += 0x7fffu + ((u >> 16) & 1u);
    return (unsigned short)(u >> 16);
}
__device__ __forceinline__ float bf2f(unsigned short u) {
    return __uint_as_float((unsigned int)u << 16);
}
__device__ __forceinline__ void addxw(f32x4& a, uint2 u) {
    a.x += bf2f((unsigned short)(u.x & 0xffff));
    a.y += bf2f((unsigned short)(u.x >> 16));
    a.z += bf2f((unsigned short)(u.y & 0xffff));
    a.w += bf2f((unsigned short)(u.y >> 16));
}

// ---------------------------------------------------------------------------
// MFMA input-projection GEMM (proven R7), transposed bf16 XWt[n][m].
// ---------------------------------------------------------------------------
__global__ __launch_bounds__(256) void gemm_xw_mfma(
    const float* __restrict__ X, int K,
    const float* __restrict__ W,
    const float* __restrict__ bias,
    unsigned short* __restrict__ XWt)
{
    extern __shared__ char gsm[];
    char* Abuf = gsm;
    char* Bbuf = gsm + 18432;

    const int tid = threadIdx.x;
    const int n0 = blockIdx.x * 128;
    const int m0 = blockIdx.y * 128;
    const int w  = tid >> 6;
    const int l  = tid & 63;
    const int lc16 = l & 15;
    const int lq4  = l >> 4;
    const int wr = w >> 1, wc = w & 1;

    const int ar  = tid >> 1;
    const int akh = tid & 1;
    const int mg  = m0 + ar;
    const float* aptr = X + (size_t)(mg & 31) * ((size_t)TSTEPS * K)
                          + (size_t)(mg >> 5) * K + akh * 16;
    const int bnp = tid & 63;
    const int bkg = tid >> 6;
    const float* bptr = W + n0 + bnp * 2;

    f32x4 acc[4][4];
    #pragma unroll
    for (int i = 0; i < 4; ++i)
        #pragma unroll
        for (int j = 0; j < 4; ++j) acc[i][j] = (f32x4){0.f, 0.f, 0.f, 0.f};

    const int KT = K >> 5;
    float4 a0, a1, a2, a3;
    float2 bw[8];

#define GLOADS(KT0) do { \
    const float* ap = aptr + (KT0) * 32; \
    a0 = *(const float4*)(ap);      a1 = *(const float4*)(ap + 4); \
    a2 = *(const float4*)(ap + 8);  a3 = *(const float4*)(ap + 12); \
    _Pragma("unroll") \
    for (int i = 0; i < 8; ++i) \
        bw[i] = *(const float2*)(bptr + (size_t)((KT0) * 32 + bkg * 8 + i) * G4); \
} while (0)

    GLOADS(0);

    for (int kt = 0; kt < KT; ++kt) {
        __syncthreads();
        {
            float av[16] = {a0.x,a0.y,a0.z,a0.w, a1.x,a1.y,a1.z,a1.w,
                            a2.x,a2.y,a2.z,a2.w, a3.x,a3.y,a3.z,a3.w};
            bf16x8 h0, h1, l0, l1;
            #pragma unroll
            for (int i = 0; i < 8; ++i) {
                unsigned short hh = f2bf(av[i]);
                h0[i] = (short)hh; l0[i] = (short)f2bf(av[i] - bf2f(hh));
                unsigned short hh2 = f2bf(av[i + 8]);
                h1[i] = (short)hh2; l1[i] = (short)f2bf(av[i + 8] - bf2f(hh2));
            }
            char* ab = Abuf + ar * 144 + akh * 32;
            *(bf16x8*)(ab)      = h0;
            *(bf16x8*)(ab + 16) = h1;
            *(bf16x8*)(ab + 64) = l0;
            *(bf16x8*)(ab + 80) = l1;
        }
        {
            bf16x8 bh[2], bl[2];
            #pragma unroll
            for (int c = 0; c < 2; ++c) {
                #pragma unroll
                for (int i = 0; i < 8; ++i) {
                    float v = c ? bw[i].y : bw[i].x;
                    unsigned short hh = f2bf(v);
                    bh[c][i] = (short)hh;
                    bl[c][i] = (short)f2bf(v - bf2f(hh));
                }
                char* bb = Bbuf + (bnp * 2 + c) * 144 + bkg * 16;
                *(bf16x8*)(bb)      = bh[c];
                *(bf16x8*)(bb + 64) = bl[c];
            }
        }
        __syncthreads();
        if (kt + 1 < KT) GLOADS(kt + 1);

        bf16x8 ah[4], al[4], bh[4], bl[4];
        #pragma unroll
        for (int rt = 0; rt < 4; ++rt) {
            const char* ab = Abuf + (wr * 64 + rt * 16 + lc16) * 144 + lq4 * 16;
            ah[rt] = *(const bf16x8*)(ab);
            al[rt] = *(const bf16x8*)(ab + 64);
        }
        #pragma unroll
        for (int ct = 0; ct < 4; ++ct) {
            const char* bb = Bbuf + (wc * 64 + ct * 16 + lc16) * 144 + lq4 * 16;
            bh[ct] = *(const bf16x8*)(bb);
            bl[ct] = *(const bf16x8*)(bb + 64);
        }
        #pragma unroll
        for (int rt = 0; rt < 4; ++rt)
            #pragma unroll
            for (int ct = 0; ct < 4; ++ct) {
                acc[rt][ct] = __builtin_amdgcn_mfma_f32_16x16x32_bf16(ah[rt], bh[ct], acc[rt][ct], 0, 0, 0);
                acc[rt][ct] = __builtin_amdgcn_mfma_f32_16x16x32_bf16(al[rt], bh[ct], acc[rt][ct], 0, 0, 0);
                acc[rt][ct] = __builtin_amdgcn_mfma_f32_16x16x32_bf16(ah[rt], bl[ct], acc[rt][ct], 0, 0, 0);
            }
    }
#undef GLOADS

    #pragma unroll
    for (int ct = 0; ct < 4; ++ct) {
        const int n = n0 + wc * 64 + ct * 16 + lc16;
        const float bn = bias[n];
        #pragma unroll
        for (int rt = 0; rt < 4; ++rt) {
            const int m = m0 + wr * 64 + rt * 16 + lq4 * 4;
            f32x4 v = acc[rt][ct];
            uint2 pk;
            pk.x = (unsigned)f2bf(v.x + bn) | ((unsigned)f2bf(v.y + bn) << 16);
            pk.y = (unsigned)f2bf(v.z + bn) | ((unsigned)f2bf(v.w + bn) << 16);
            *(uint2*)(XWt + (size_t)n * MTOT + m) = pk;
        }
    }
}

// ---------------------------------------------------------------------------
// MFMA recurrent scan (R7 protocol, bank-conflict-free LDS, h in bf16-hi only).
// 32 blocks x 256 thr (4 waves), dir = blk&1, P = blk>>1. Wave w owns h-cols
// [P*32 + w*8, +8) -> 32 zc; Wh hi/lo fragments in registers (3->2 products:
// ah*Wh_hi + ah*Wh_lo; h published as bf16 hi plane only).
// HST layout [k16 0..63][b 0..31][16B], row stride 528B -> conflict-free b128.
// ZL layout [zc 0..127][b] stride 33 words -> conflict-free gate reads.
// ---------------------------------------------------------------------------
__global__ __launch_bounds__(256, 1) void lstm_scan9(
    const unsigned short* __restrict__ xw_f,   // [G4][MTOT] bf16
    const unsigned short* __restrict__ xw_b,
    const float* __restrict__ Wh_f,            // [512][2048] f32
    const float* __restrict__ Wh_b,
    float* __restrict__ out,                   // [B][T][1024] f32
    unsigned short* __restrict__ hbuf,         // [dir][par][P][b][32c] bf16 hi
    int* __restrict__ flags,                   // [dir][TSTEPS][16]
    int lval)                                  // layer+1
{
    extern __shared__ char smem[];
    float* ZL = (float*)(smem + HSZ);          // [128 zc][33]

    const int tid  = threadIdx.x;
    const int l    = tid & 63;
    const int w    = tid >> 6;
    const int dir  = blockIdx.x & 1;
    const int P    = blockIdx.x >> 1;
    const int p_eff = P * 4 + w;
    const int lc16 = l & 15;
    const int lq4  = l >> 4;

    const unsigned short* __restrict__ xw = dir ? xw_b : xw_f;
    const float* __restrict__ Wh = dir ? Wh_b : Wh_f;
    char* hb  = (char*)hbuf + (size_t)dir * 65536;   // 32KB per parity, hi only
    int*  flg = flags + dir * TSTEPS * 16;

    // ---- one-time: Wh fragments -> registers (hi/lo bf16) ----
    bf16x8 wfh[16][2], wfl[16][2];
    #pragma unroll
    for (int ki = 0; ki < 16; ++ki) {
        #pragma unroll
        for (int ct = 0; ct < 2; ++ct) {
            const int zc  = ct * 16 + lc16;
            const int col = p_eff * 8 + (zc & 7) + 512 * (zc >> 3);
            const float* src = Wh + (size_t)(ki * 32 + lq4 * 8) * G4 + col;
            bf16x8 vh, vl;
            #pragma unroll
            for (int r = 0; r < 8; ++r) {
                float v = src[(size_t)r * G4];
                unsigned short h16 = f2bf(v);
                vh[r] = (short)h16;
                vl[r] = (short)f2bf(v - bf2f(h16));
            }
            wfh[ki][ct] = vh;
            wfl[ki][ct] = vl;
        }
    }

    const int gc0 = p_eff * 8 + (lc16 & 7) + 512 * (lc16 >> 3);
    const unsigned short* xc0 = xw + (size_t)gc0 * MTOT;
    const unsigned short* xc1 = xw + (size_t)(gc0 + 1024) * MTOT;

    const int gb = tid & 31;                   // gate-thread batch
    const int jg = tid >> 5;                   // col group (cols jg*4..+3)
    float* outg = out + (size_t)gb * TSTEPS * OUTW + dir * HID + P * 32 + jg * 4;
    float cq[4] = {0.f, 0.f, 0.f, 0.f};

    for (int s = 0; s < TSTEPS; ++s) {
        const int t = dir ? (TSTEPS - 1 - s) : s;

        const int xoff = t * 32 + lq4 * 4;
        uint2 u00 = *(const uint2*)(xc0 + xoff);
        uint2 u10 = *(const uint2*)(xc0 + xoff + 16);
        uint2 u01 = *(const uint2*)(xc1 + xoff);
        uint2 u11 = *(const uint2*)(xc1 + xoff + 16);

        f32x4 acc00 = {0,0,0,0}, acc01 = {0,0,0,0}, acc10 = {0,0,0,0}, acc11 = {0,0,0,0};

        if (s > 0) {
            // ---- poll the 16 per-producer flag slots (proven R7 pattern) ----
            {
                const int* fp = &flg[(s - 1) * 16 + (l & 15)];
                int fv;
                do {
                    asm volatile("global_load_dword %0, %1, off sc0 sc1\n\t"
                                 "s_waitcnt vmcnt(0)"
                                 : "=v"(fv) : "v"(fp) : "memory");
                } while (__any(fv != lval));
            }
            // ---- issue 8 staging loads (32KB hi plane), then barrier ----
            const char* hsrc = hb + ((s - 1) & 1) * 32768;
            float4 rg[8];
            #pragma unroll
            for (int c = 0; c < 8; ++c) {
                const char* sp = hsrc + c * 4096 + tid * 16;
                asm volatile("global_load_dwordx4 %0, %1, off sc0 sc1"
                             : "=v"(rg[c]) : "v"(sp) : "memory");
            }
            __syncthreads();   // prev step's LDS reads complete before overwrite

            // decode: ip=c*4096+tid*16 -> Pq=ip>>11, b=(ip>>6)&31, jb=ip&63
            // LDS addr = (Pq*4 + jb/16)*KROW + b*16  (conflict-free by design)
#define STG_WRITE(C0) do { \
            _Pragma("unroll") \
            for (int c = (C0); c < (C0) + 4; ++c) { \
                const int ip  = c * 4096 + tid * 16; \
                const int Pq  = ip >> 11; \
                const int b   = (ip >> 6) & 31; \
                const int jb  = ip & 63; \
                *(float4*)(smem + (Pq * 4 + (jb >> 4)) * KROW + b * 16) = rg[c]; \
            } } while (0)
            asm volatile("s_waitcnt vmcnt(4)" ::: "memory");
            __builtin_amdgcn_sched_barrier(0);
            STG_WRITE(0);
            asm volatile("s_waitcnt vmcnt(0)" ::: "memory");
            __builtin_amdgcn_sched_barrier(0);
            STG_WRITE(4);
#undef STG_WRITE
            __syncthreads();

            // ---- MFMA: A (h hi) from LDS, B (Wh hi+lo) from registers ----
            #pragma unroll
            for (int ki = 0; ki < 16; ++ki) {
                const char* ra = smem + (ki * 4 + lq4) * KROW + lc16 * 16;
                bf16x8 ah0 = *(const bf16x8*)ra;
                bf16x8 ah1 = *(const bf16x8*)(ra + 256);
                acc00 = __builtin_amdgcn_mfma_f32_16x16x32_bf16(ah0, wfh[ki][0], acc00, 0, 0, 0);
                acc10 = __builtin_amdgcn_mfma_f32_16x16x32_bf16(ah1, wfh[ki][0], acc10, 0, 0, 0);
                acc01 = __builtin_amdgcn_mfma_f32_16x16x32_bf16(ah0, wfh[ki][1], acc01, 0, 0, 0);
                acc11 = __builtin_amdgcn_mfma_f32_16x16x32_bf16(ah1, wfh[ki][1], acc11, 0, 0, 0);
                acc00 = __builtin_amdgcn_mfma_f32_16x16x32_bf16(ah0, wfl[ki][0], acc00, 0, 0, 0);
                acc10 = __builtin_amdgcn_mfma_f32_16x16x32_bf16(ah1, wfl[ki][0], acc10, 0, 0, 0);
                acc01 = __builtin_amdgcn_mfma_f32_16x16x32_bf16(ah0, wfl[ki][1], acc01, 0, 0, 0);
                acc11 = __builtin_amdgcn_mfma_f32_16x16x32_bf16(ah1, wfl[ki][1], acc11, 0, 0, 0);
            }
        }

        // ---- add xw ----
        addxw(acc00, u00); addxw(acc10, u10);
        addxw(acc01, u01); addxw(acc11, u11);

        // ---- z -> ZL[zc][b], stride 33 ----
        {
            const int cb = w * 32 + lc16;
            const int r0 = lq4 * 4;
            #pragma unroll
            for (int i = 0; i < 4; ++i) {
                ZL[cb * 33 + r0 + i]             = acc00[i];
                ZL[cb * 33 + 16 + r0 + i]        = acc10[i];
                ZL[(cb + 16) * 33 + r0 + i]      = acc01[i];
                ZL[(cb + 16) * 33 + 16 + r0 + i] = acc11[i];
            }
        }
        __syncthreads();

        // ---- gates: thread (b=gb, cols jg*4..+3); publish bf16 hi ----
        float hv[4];
        {
            #pragma unroll
            for (int q = 0; q < 4; ++q) {
                const int j  = jg * 4 + q;         // block-local h-col 0..31
                const int wv = j >> 3;
                const int jj = j & 7;
                const int zb = wv * 32;
                float zi = ZL[(zb + jj) * 33 + gb];
                float zf = ZL[(zb + 8 + jj) * 33 + gb];
                float zg = ZL[(zb + 16 + jj) * 33 + gb];
                float zo = ZL[(zb + 24 + jj) * 33 + gb];
                float ig = sigf(zi);
                float fg = sigf(zf);
                float gg = tanhf_fast(zg);
                float og = sigf(zo);
                cq[q] = fmaf(fg, cq[q], ig * gg);
                hv[q] = og * tanhf_fast(cq[q]);
            }
            unsigned short h0 = f2bf(hv[0]), h1 = f2bf(hv[1]);
            unsigned short h2 = f2bf(hv[2]), h3 = f2bf(hv[3]);
            uint2 hi_pk;
            hi_pk.x = (unsigned)h0 | ((unsigned)h1 << 16);
            hi_pk.y = (unsigned)h2 | ((unsigned)h3 << 16);
            char* wp = hb + (s & 1) * 32768 + P * 2048 + gb * 64 + jg * 8;
            asm volatile("global_store_dwordx2 %0, %1, off sc0 sc1"
                         :: "v"(wp), "v"(hi_pk) : "memory");
        }
        asm volatile("s_waitcnt vmcnt(0)" ::: "memory");  // h stores at MALL
        __syncthreads();                                  // ...for ALL waves
        if (tid == 0) {
            int* fp = &flg[s * 16 + P];
            asm volatile("global_store_dword %0, %1, off sc0 sc1"
                         :: "v"(fp), "v"(lval) : "memory");
        }
        // output store off the critical path
        float4 ov; ov.x = hv[0]; ov.y = hv[1]; ov.z = hv[2]; ov.w = hv[3];
        *(float4*)&outg[(size_t)t * OUTW] = ov;
    }
}

extern "C" void kernel_launch(void* const* d_in, const int* in_sizes, int n_in,
                              void* d_out, int out_size, void* d_ws, size_t ws_size,
                              hipStream_t stream)
{
    const float* x     = (const float*)d_in[0];
    const float* Wi_f0 = (const float*)d_in[1];
    const float* Wh_f0 = (const float*)d_in[2];
    const float* b_f0  = (const float*)d_in[3];
    const float* Wi_b0 = (const float*)d_in[4];
    const float* Wh_b0 = (const float*)d_in[5];
    const float* b_b0  = (const float*)d_in[6];
    const float* Wi_f1 = (const float*)d_in[7];
    const float* Wh_f1 = (const float*)d_in[8];
    const float* b_f1  = (const float*)d_in[9];
    const float* Wi_b1 = (const float*)d_in[10];
    const float* Wh_b1 = (const float*)d_in[11];
    const float* b_b1  = (const float*)d_in[12];
    float* out = (float*)d_out;

    const size_t xw_elems = (size_t)MTOT * G4;                 // 33,554,432
    unsigned short* xwf = (unsigned short*)d_ws;
    unsigned short* xwb = xwf + xw_elems;
    char* tail = (char*)d_ws + 2 * xw_elems * sizeof(unsigned short);  // 128 MiB
    unsigned short* hbuf = (unsigned short*)tail;              // [dir][2 par][32KB]
    int* flags = (int*)(tail + 262144);                        // [dir][512][16]

    (void)hipMemsetAsync(flags, 0, 2 * TSTEPS * 16 * sizeof(int), stream);

    dim3 ggrid(G4 / 128, MTOT / 128);                          // (16, 128)
    dim3 gblock(256);
    const size_t gsmem = 36864;
    dim3 sgrid(2 * NBLK);                                      // 32 blocks
    dim3 sblock(256);
    const size_t ssmem = HSZ + 128 * 33 * 4;                   // 50,688 B

    gemm_xw_mfma<<<ggrid, gblock, gsmem, stream>>>(x, 256, Wi_f0, b_f0, xwf);
    gemm_xw_mfma<<<ggrid, gblock, gsmem, stream>>>(x, 256, Wi_b0, b_b0, xwb);
    lstm_scan9<<<sgrid, sblock, ssmem, stream>>>(xwf, xwb, Wh_f0, Wh_b0, out,
                                                 hbuf, flags, 1);
    gemm_xw_mfma<<<ggrid, gblock, gsmem, stream>>>(out, 1024, Wi_f1, b_f1, xwf);
    gemm_xw_mfma<<<ggrid, gblock, gsmem, stream>>>(out, 1024, Wi_b1, b_b1, xwb);
    lstm_scan9<<<sgrid, sblock, ssmem, stream>>>(xwf, xwb, Wh_f1, Wh_b1, out,
                                                 hbuf, flags, 2);
}